// Round 3
// baseline (1207.776 us; speedup 1.0000x reference)
//
#include <hip/hip_runtime.h>

// TriPlanePC2Encoder: scatter-mean of point features onto 3 canonical planes.
// B=8, N=200000, C=32, R=128. out[b, plane, c, row, col], plane order xy,yz,xz.
//
// Round 8: super-bin sort (512 sbins of 32 bins) + group-private LDS accum.
//   bin -> count (512-entry LDS hist per (bp,split)) -> sscan (512-wide scan,
//   per-split offsets) -> reorder (LDS cursors, ~24-entry runs => write-
//   combined, killing R5's 16x write amp) -> transpose (feat -> point-major
//   bf16) -> gather (32-lane group = 1 sbin; flat batches of 8 points, 8
//   independent 64B coalesced loads in flight; group-private skewed LDS
//   acc[32][32], zero barriers; in-kernel counting; coalesced stores).
// R6 lesson: global atomic-with-return per point = latency death.
// R7 lesson: 4-points-in-flight per group = latency death. MLP depth rules.
// entry = (point_id << 5) | (bin & 31); pid < 2^18 -> fits u32.

constexpr int R     = 128;
constexpr int NBINS = R * R;        // 16384
constexpr int NPTS  = 200000;
constexpr int NB    = 8;
constexpr int NC    = 32;
constexpr int SPLIT = 16;           // tiles per (b,plane)
constexpr int TILE  = NPTS / SPLIT; // 12500
constexpr int NSB   = 512;          // super-bins (32 bins each)

// ws layout:
//  phase1 (dead after reorder, overlaid by ftT later):
//    bins  u16 [3][NB][NPTS]       @ 0           (9,600,000)
//    scntS u16 [24][16][512]       @ 9,600,000   (393,216)
//    soffS u32 [24][16][512]       @ 9,993,216   (786,432)   end 10,779,648
//  phase2: ftT bf16 [NB][NPTS][NC] @ 0           (102,400,000)
//  persistent tail:
//    soff u32 [24][513]            @ 102,400,000 (49,248)
//    ENT  u32 [24][NPTS]           @ 102,449,280 (19,200,000) end 121,649,280
constexpr size_t OFF_SCNT  = 9600000;
constexpr size_t OFF_SOFFS = 9993216;
constexpr size_t OFF_SOFF  = 102400000;
constexpr size_t OFF_ENT   = 102449280;
constexpr size_t WS_NEED   = 121649280;
constexpr size_t OFF_TOT   = 9600000;   // fallback-only cnt region

__device__ __forceinline__ int coord_bin(float p) {
    // xyz_norm = (p+1)/2 - 0.5 ; then /(1+eps) + 0.5 ; clip ; *R ; trunc
    float v = (p + 1.0f) * 0.5f - 0.5f;
    float t = v / 1.00001f + 0.5f;                     // IEEE fp32 divide
    t = fminf(fmaxf(t, 0.0f), (float)(1.0 - 1e-5));
    return (int)(t * 128.0f);
}

__global__ __launch_bounds__(256) void bin_kernel(
    const float* __restrict__ xyz, unsigned short* __restrict__ bins) {
    int i = blockIdx.x * 256 + threadIdx.x;            // over B*N
    if (i >= NB * NPTS) return;
    float x = xyz[3 * (size_t)i + 0];
    float y = xyz[3 * (size_t)i + 1];
    float z = xyz[3 * (size_t)i + 2];
    int ix = coord_bin(x), iy = coord_bin(y), iz = coord_bin(z);
    // plane dims: xy=(0,1) yz=(1,2) xz=(0,2); lin = idx_d0 + R*idx_d1
    bins[0 * (size_t)NB * NPTS + i] = (unsigned short)(ix + R * iy);
    bins[1 * (size_t)NB * NPTS + i] = (unsigned short)(iy + R * iz);
    bins[2 * (size_t)NB * NPTS + i] = (unsigned short)(ix + R * iz);
}

// Per-(bp,split) 512-entry super-bin histogram -> scntS u16.
__global__ __launch_bounds__(1024) void count_kernel(
    const unsigned short* __restrict__ bins, unsigned short* __restrict__ scntS) {
    __shared__ unsigned h[NSB];
    int blk   = blockIdx.x;
    int split = blk & (SPLIT - 1);
    int bp    = blk >> 4;
    int b     = bp / 3, plane = bp - 3 * b;
    if (threadIdx.x < NSB) h[threadIdx.x] = 0u;
    __syncthreads();
    const unsigned* src = (const unsigned*)(bins + ((size_t)plane * NB + b) * NPTS
                                                 + (size_t)split * TILE);
    for (int j = threadIdx.x; j < TILE / 2; j += 1024) {
        unsigned u = src[j];
        atomicAdd(&h[(u & 0xffffu) >> 5], 1u);
        atomicAdd(&h[(u >> 16) >> 5], 1u);
    }
    __syncthreads();
    unsigned short* dst = scntS + (size_t)blk * NSB;
    if (threadIdx.x < NSB) dst[threadIdx.x] = (unsigned short)h[threadIdx.x];
}

// Per-bp: per-split running offsets + block-wide exclusive scan of 512 sbins.
__global__ __launch_bounds__(512) void sscan_kernel(
    const unsigned short* __restrict__ scntS, unsigned* __restrict__ soffS,
    unsigned* __restrict__ soff) {
    __shared__ unsigned ts[NSB];
    int bp = blockIdx.x, t = threadIdx.x;
    const unsigned short* cb = scntS + (size_t)bp * SPLIT * NSB;
    unsigned rel[SPLIT];
    unsigned run = 0;
#pragma unroll
    for (int s = 0; s < SPLIT; ++s) {
        rel[s] = run;
        run += cb[(size_t)s * NSB + t];
    }
    ts[t] = run;
    __syncthreads();
    for (int o = 1; o < NSB; o <<= 1) {                // Hillis-Steele incl.
        unsigned a = (t >= o) ? ts[t - o] : 0u;
        __syncthreads();
        ts[t] += a;
        __syncthreads();
    }
    unsigned base = ts[t] - run;                       // exclusive
    unsigned* osb = soffS + (size_t)bp * SPLIT * NSB;
#pragma unroll
    for (int s = 0; s < SPLIT; ++s) osb[(size_t)s * NSB + t] = base + rel[s];
    soff[bp * 513 + t] = base;
    if (t == NSB - 1) soff[bp * 513 + NSB] = ts[t];    // sentinel = NPTS
}

// Super-bin sort via per-split LDS cursors (R5 design at 512 granularity).
// Runs per (split,sbin) ~24 entries -> L2 write-combines -> low write amp.
__global__ __launch_bounds__(1024) void reorder_kernel(
    const unsigned short* __restrict__ bins, const unsigned* __restrict__ soffS,
    unsigned* __restrict__ ENT) {
    __shared__ unsigned cur[NSB];
    int blk   = blockIdx.x;
    int split = blk & (SPLIT - 1);
    int bp    = blk >> 4;
    int b     = bp / 3, plane = bp - 3 * b;
    const unsigned* osb = soffS + (size_t)blk * NSB;
    if (threadIdx.x < NSB) cur[threadIdx.x] = osb[threadIdx.x];
    __syncthreads();
    const unsigned* src = (const unsigned*)(bins + ((size_t)plane * NB + b) * NPTS
                                                 + (size_t)split * TILE);
    unsigned nbase = (unsigned)(split * TILE);
    unsigned* ep = ENT + (size_t)bp * NPTS;
    for (int j = threadIdx.x; j < TILE / 2; j += 1024) {
        unsigned u  = src[j];
        unsigned l0 = u & 0xffffu, l1 = u >> 16;
        unsigned p0 = atomicAdd(&cur[l0 >> 5], 1u);
        ep[p0] = ((nbase + 2u * j) << 5) | (l0 & 31u);
        unsigned p1 = atomicAdd(&cur[l1 >> 5], 1u);
        ep[p1] = ((nbase + 2u * j + 1u) << 5) | (l1 & 31u);
    }
}

// feat (b, C, N) fp32 -> ftT (b, n, c) bf16 (RNE). One point = 64 B line.
constexpr int TTILES = (NPTS + 255) / 256;   // 782
__global__ __launch_bounds__(256) void transpose_kernel(
    const float* __restrict__ feat, unsigned short* __restrict__ ftT) {
    int b = blockIdx.x / TTILES;
    int n = (blockIdx.x % TTILES) * 256 + threadIdx.x;
    if (n >= NPTS) return;
    const float* fb = feat + (size_t)b * NC * NPTS + n;
    unsigned pk[16];
#pragma unroll
    for (int c = 0; c < 16; ++c) {
        unsigned u0 = __float_as_uint(fb[(size_t)(2 * c) * NPTS]);
        unsigned u1 = __float_as_uint(fb[(size_t)(2 * c + 1) * NPTS]);
        unsigned r0 = (u0 + 0x7fffu + ((u0 >> 16) & 1u)) >> 16;   // bf16 RNE
        unsigned r1 = (u1 + 0x7fffu + ((u1 >> 16) & 1u)) >> 16;
        pk[c] = r0 | (r1 << 16);
    }
    uint4* dst = (uint4*)(ftT + ((size_t)b * NPTS + n) * NC);
#pragma unroll
    for (int q = 0; q < 4; ++q)
        dst[q] = make_uint4(pk[4 * q], pk[4 * q + 1], pk[4 * q + 2], pk[4 * q + 3]);
}

__device__ __forceinline__ float bf2f(unsigned short h) {
    return __uint_as_float((unsigned)h << 16);
}

// 32-lane group = 1 sbin (32 bins). Flat 8-point batches: 8 broadcast ENT
// loads + 8 independent coalesced 64B ftT loads in flight per group.
// Group-private LDS acc[32 bins][32 ch] fp32, diagonal skew (2-way max =
// free). Counts via one masked ds_add per batch. Same-wave LDS ordering ->
// zero barriers. Epilogue: lane = bin -> 128B coalesced stores per group.
__global__ __launch_bounds__(128) void gather_kernel(
    const unsigned* __restrict__ soff, const unsigned* __restrict__ ENT,
    const unsigned short* __restrict__ ftT, float* __restrict__ out) {
    __shared__ float lsh[4 * 1056];                    // 4 groups x (1024+32)
    int g = threadIdx.x >> 5, c = threadIdx.x & 31;
    int blk = blockIdx.x;
    int bp  = blk >> 7;                                // 128 blocks per bp
    int sb  = ((blk & 127) << 2) | g;                  // group's super-bin
    int b   = bp / 3;
    float* acc  = lsh + g * 1056;
    float* cntf = acc + 1024;
    for (int i = c; i < 1056; i += 32) acc[i] = 0.0f;  // group-private init
    unsigned s = soff[bp * 513 + sb], e = soff[bp * 513 + sb + 1];
    const unsigned* Ep = ENT + (size_t)bp * NPTS;
    const unsigned short* fbc = ftT + (size_t)b * NPTS * NC + c;
    unsigned p = s;
    for (; p + 8 <= e; p += 8) {
        unsigned en0 = Ep[p],     en1 = Ep[p + 1], en2 = Ep[p + 2], en3 = Ep[p + 3];
        unsigned en4 = Ep[p + 4], en5 = Ep[p + 5], en6 = Ep[p + 6], en7 = Ep[p + 7];
        float v0 = bf2f(fbc[(size_t)(en0 >> 5) * NC]);
        float v1 = bf2f(fbc[(size_t)(en1 >> 5) * NC]);
        float v2 = bf2f(fbc[(size_t)(en2 >> 5) * NC]);
        float v3 = bf2f(fbc[(size_t)(en3 >> 5) * NC]);
        float v4 = bf2f(fbc[(size_t)(en4 >> 5) * NC]);
        float v5 = bf2f(fbc[(size_t)(en5 >> 5) * NC]);
        float v6 = bf2f(fbc[(size_t)(en6 >> 5) * NC]);
        float v7 = bf2f(fbc[(size_t)(en7 >> 5) * NC]);
        unsigned b0 = en0 & 31u, b1 = en1 & 31u, b2 = en2 & 31u, b3 = en3 & 31u;
        unsigned b4 = en4 & 31u, b5 = en5 & 31u, b6 = en6 & 31u, b7 = en7 & 31u;
        atomicAdd(&acc[b0 * 32 + ((c + b0) & 31)], v0);
        atomicAdd(&acc[b1 * 32 + ((c + b1) & 31)], v1);
        atomicAdd(&acc[b2 * 32 + ((c + b2) & 31)], v2);
        atomicAdd(&acc[b3 * 32 + ((c + b3) & 31)], v3);
        atomicAdd(&acc[b4 * 32 + ((c + b4) & 31)], v4);
        atomicAdd(&acc[b5 * 32 + ((c + b5) & 31)], v5);
        atomicAdd(&acc[b6 * 32 + ((c + b6) & 31)], v6);
        atomicAdd(&acc[b7 * 32 + ((c + b7) & 31)], v7);
        unsigned esel = en0;                            // lane k<8 counts pt k
        esel = (c == 1) ? en1 : esel;
        esel = (c == 2) ? en2 : esel;
        esel = (c == 3) ? en3 : esel;
        esel = (c == 4) ? en4 : esel;
        esel = (c == 5) ? en5 : esel;
        esel = (c == 6) ? en6 : esel;
        esel = (c == 7) ? en7 : esel;
        if (c < 8) atomicAdd(&cntf[esel & 31u], 1.0f);
    }
    for (; p < e; ++p) {
        unsigned en = Ep[p];
        float v = bf2f(fbc[(size_t)(en >> 5) * NC]);
        unsigned bb = en & 31u;
        atomicAdd(&acc[bb * 32 + ((c + bb) & 31)], v);
        if (c == 0) atomicAdd(&cntf[bb], 1.0f);
    }
    // epilogue: lane = bin l within sbin; counts exact in fp32 (< 2^24)
    int l = c;
    float inv = 1.0f / fmaxf(cntf[l], 1.0f);           // empty bins -> 0
    float* ob = out + (size_t)bp * NC * NBINS + (size_t)sb * 32 + l;
#pragma unroll
    for (int cc = 0; cc < NC; ++cc)
        ob[(size_t)cc * NBINS] = acc[l * 32 + ((cc + l) & 31)] * inv;
}

// ---------- fallback (round-3 verified path; needs only bins + cnt) ----------
constexpr int CHUNKS = NPTS / 8;
__global__ __launch_bounds__(1024) void count_fb_kernel(
    const unsigned short* __restrict__ bins, unsigned* __restrict__ cnt) {
    __shared__ unsigned hist[NBINS];
    int blk   = blockIdx.x;
    int split = blk & (SPLIT - 1);
    int bp    = blk >> 4;
    int b     = bp / 3, plane = bp - 3 * b;
    for (int i = threadIdx.x; i < NBINS; i += 1024) hist[i] = 0u;
    __syncthreads();
    const unsigned short* src = bins + ((size_t)plane * NB + b) * NPTS
                                     + (size_t)split * TILE;
    for (int n = threadIdx.x; n < TILE; n += 1024) atomicAdd(&hist[src[n]], 1u);
    __syncthreads();
    unsigned* dst = cnt + (size_t)bp * NBINS;
    for (int i = threadIdx.x; i < NBINS; i += 1024) {
        unsigned v = hist[i];
        if (v) atomicAdd(&dst[i], v);
    }
}
__global__ __launch_bounds__(1024) void scatter_kernel(
    const unsigned short* __restrict__ bins, const float* __restrict__ feat,
    const unsigned* __restrict__ cnt, float* __restrict__ out) {
    __shared__ float hist[NBINS];
    int blk = blockIdx.x, b = blk / 96;
    int rem = blk - b * 96, plane = rem >> 5, ch = rem & 31;
    for (int i = threadIdx.x; i < NBINS; i += 1024) hist[i] = 0.0f;
    __syncthreads();
    const uint4*  bp4 = (const uint4*)(bins + ((size_t)plane * NB + b) * NPTS);
    const float4* fp4 = (const float4*)(feat + ((size_t)b * NC + ch) * NPTS);
    for (int p = threadIdx.x; p < CHUNKS; p += 1024) {
        uint4 bb = bp4[p];
        float4 f0 = fp4[2 * p], f1 = fp4[2 * p + 1];
        atomicAdd(&hist[bb.x & 0xffffu], f0.x);
        atomicAdd(&hist[bb.x >> 16],     f0.y);
        atomicAdd(&hist[bb.y & 0xffffu], f0.z);
        atomicAdd(&hist[bb.y >> 16],     f0.w);
        atomicAdd(&hist[bb.z & 0xffffu], f1.x);
        atomicAdd(&hist[bb.z >> 16],     f1.y);
        atomicAdd(&hist[bb.w & 0xffffu], f1.z);
        atomicAdd(&hist[bb.w >> 16],     f1.w);
    }
    __syncthreads();
    const unsigned* cb = cnt + (size_t)(b * 3 + plane) * NBINS;
    float* ob = out + (((size_t)b * 3 + plane) * NC + ch) * (size_t)NBINS;
    for (int i = threadIdx.x; i < NBINS; i += 1024)
        ob[i] = hist[i] / fmaxf((float)cb[i], 1.0f);
}

extern "C" void kernel_launch(void* const* d_in, const int* in_sizes, int n_in,
                              void* d_out, int out_size, void* d_ws, size_t ws_size,
                              hipStream_t stream) {
    const float* xyz  = (const float*)d_in[0];         // (B, N, 3)
    const float* feat = (const float*)d_in[1];         // (B, C, N)
    float* out = (float*)d_out;                        // (B, 3, C, R, R)
    char* ws = (char*)d_ws;
    unsigned short* bins = (unsigned short*)ws;

    int total_pts = NB * NPTS;
    bin_kernel<<<(total_pts + 255) / 256, 256, 0, stream>>>(xyz, bins);

    if (ws_size >= WS_NEED) {
        unsigned short* scntS = (unsigned short*)(ws + OFF_SCNT);
        unsigned* soffS = (unsigned*)(ws + OFF_SOFFS);
        unsigned* soff  = (unsigned*)(ws + OFF_SOFF);
        unsigned* ENT   = (unsigned*)(ws + OFF_ENT);
        unsigned short* ftT = (unsigned short*)ws;     // overlays phase-1 bufs
        count_kernel<<<NB * 3 * SPLIT, 1024, 0, stream>>>(bins, scntS);
        sscan_kernel<<<NB * 3, 512, 0, stream>>>(scntS, soffS, soff);
        reorder_kernel<<<NB * 3 * SPLIT, 1024, 0, stream>>>(bins, soffS, ENT);
        transpose_kernel<<<NB * TTILES, 256, 0, stream>>>(feat, ftT);  // after reorder!
        gather_kernel<<<NB * 3 * 128, 128, 0, stream>>>(soff, ENT, ftT, out);
    } else {
        unsigned* cnt = (unsigned*)(ws + OFF_TOT);
        hipMemsetAsync(cnt, 0, (size_t)NB * 3 * NBINS * sizeof(unsigned), stream);
        count_fb_kernel<<<NB * 3 * SPLIT, 1024, 0, stream>>>(bins, cnt);
        scatter_kernel<<<NB * 3 * NC, 1024, 0, stream>>>(bins, feat, cnt, out);
    }
}

// Round 4
// 527.650 us; speedup vs baseline: 2.2890x; 2.2890x over previous
//
#include <hip/hip_runtime.h>

// TriPlanePC2Encoder: scatter-mean of point features onto 3 canonical planes.
// B=8, N=200000, C=32, R=128. out[b, plane, c, row, col], plane order xy,yz,xz.
//
// Round 9: recombination of the two proven-fast halves.
//   R5 sort pipeline (count -> scan -> LDS-cursor reorder, benched in the
//   607us run) + R6 gather (bin-per-lane, register accumulation, benched
//   fast in the R6 run). R6's global-atomic reorder (400us) is dropped.
// R6 lesson: global atomic-with-return per point = latency death.
// R7/R8 lesson: group-uniform index loads + LDS fp32 atomic accumulation
//   runs ~15x below the latency model (mechanism unresolved); per-lane
//   private addresses + register accumulation is the proven fast pattern.

constexpr int R     = 128;
constexpr int NBINS = R * R;        // 16384
constexpr int NPTS  = 200000;
constexpr int NB    = 8;
constexpr int NC    = 32;
constexpr int SPLIT = 16;           // sort tiles per (b,plane)
constexpr int TILE  = NPTS / SPLIT; // 12500 (fits u16 counts)

// ws layout (identical to the proven 607us run):
//  phase1 (dead after reorder, overlaid by ftT later):
//    bins u16 [3][NB][NPTS]        @ 0           (9,600,000)
//    cntS u16 [24][SPLIT][NBINS]   @ 9,600,000   (12,582,912)
//    offS u32 [24][SPLIT][NBINS]   @ 22,182,912  (25,165,824)  end 47,348,736
//  phase2: ftT bf16 [NB][NPTS][NC] @ 0           (102,400,000)
//  persistent tail:
//    off  u32 [24][NBINS]          @ 102,400,000 (1,572,864)
//    S    u32 [24][NPTS]           @ 103,972,864 (19,200,000)  end 123,172,864
constexpr size_t OFF_CNTS = 9600000;
constexpr size_t OFF_OFFS = 22182912;
constexpr size_t OFF_OFF  = 102400000;
constexpr size_t OFF_S    = 103972864;
constexpr size_t WS_NEED  = 123172864;

__device__ __forceinline__ int coord_bin(float p) {
    // xyz_norm = (p+1)/2 - 0.5 ; then /(1+eps) + 0.5 ; clip ; *R ; trunc
    float v = (p + 1.0f) * 0.5f - 0.5f;
    float t = v / 1.00001f + 0.5f;                     // IEEE fp32 divide
    t = fminf(fmaxf(t, 0.0f), (float)(1.0 - 1e-5));
    return (int)(t * 128.0f);
}

__global__ __launch_bounds__(256) void bin_kernel(
    const float* __restrict__ xyz, unsigned short* __restrict__ bins) {
    int i = blockIdx.x * 256 + threadIdx.x;            // over B*N
    if (i >= NB * NPTS) return;
    float x = xyz[3 * (size_t)i + 0];
    float y = xyz[3 * (size_t)i + 1];
    float z = xyz[3 * (size_t)i + 2];
    int ix = coord_bin(x), iy = coord_bin(y), iz = coord_bin(z);
    // plane dims: xy=(0,1) yz=(1,2) xz=(0,2); lin = idx_d0 + R*idx_d1
    bins[0 * (size_t)NB * NPTS + i] = (unsigned short)(ix + R * iy);
    bins[1 * (size_t)NB * NPTS + i] = (unsigned short)(iy + R * iz);
    bins[2 * (size_t)NB * NPTS + i] = (unsigned short)(ix + R * iz);
}

// Per-(bp,split) u16 histogram. blk = bp*SPLIT + split.
__global__ __launch_bounds__(1024) void count_kernel(
    const unsigned short* __restrict__ bins, unsigned short* __restrict__ cntS) {
    __shared__ unsigned hist[NBINS];
    int blk   = blockIdx.x;
    int split = blk & (SPLIT - 1);
    int bp    = blk >> 4;
    int b     = bp / 3, plane = bp - 3 * b;
    for (int i = threadIdx.x; i < NBINS; i += 1024) hist[i] = 0u;
    __syncthreads();
    const unsigned* src = (const unsigned*)(bins + ((size_t)plane * NB + b) * NPTS
                                                 + (size_t)split * TILE);
    for (int j = threadIdx.x; j < TILE / 2; j += 1024) {
        unsigned u = src[j];
        atomicAdd(&hist[u & 0xffffu], 1u);
        atomicAdd(&hist[u >> 16], 1u);
    }
    __syncthreads();
    unsigned short* dst = cntS + (size_t)blk * NBINS;
    for (int i = threadIdx.x; i < NBINS; i += 1024)
        dst[i] = (unsigned short)hist[i];
}

// Per-bp: cross-split + cross-bin exclusive scan. Writes per-split offsets
// (reorder) and per-bin base offsets (gather). 24 blocks x 1024 thr x 16 bins.
__global__ __launch_bounds__(1024) void scan_kernel(
    const unsigned short* __restrict__ cntS, unsigned* __restrict__ off,
    unsigned* __restrict__ offS) {
    __shared__ unsigned tsum[1024];
    int bp = blockIdx.x, t = threadIdx.x;
    const unsigned short* cb = cntS + (size_t)bp * SPLIT * NBINS;
    int base = t * 16;
    unsigned tot[16], v[16];
#pragma unroll
    for (int k = 0; k < 16; ++k) {
        unsigned r = 0;
        for (int s = 0; s < SPLIT; ++s) r += cb[(size_t)s * NBINS + base + k];
        tot[k] = r;
    }
    unsigned run = 0;
#pragma unroll
    for (int k = 0; k < 16; ++k) { v[k] = run; run += tot[k]; }
    tsum[t] = run;
    __syncthreads();
    for (int o = 1; o < 1024; o <<= 1) {           // Hillis-Steele inclusive
        unsigned a = (t >= o) ? tsum[t - o] : 0u;
        __syncthreads();
        tsum[t] += a;
        __syncthreads();
    }
    unsigned tb = (t > 0) ? tsum[t - 1] : 0u;
    unsigned* ob  = off  + (size_t)bp * NBINS;
    unsigned* osb = offS + (size_t)bp * SPLIT * NBINS;
#pragma unroll
    for (int k = 0; k < 16; ++k) {
        unsigned bb = tb + v[k];
        ob[base + k] = bb;
        unsigned r = 0;
        for (int s = 0; s < SPLIT; ++s) {
            osb[(size_t)s * NBINS + base + k] = bb + r;
            r += cb[(size_t)s * NBINS + base + k];
        }
    }
}

// Bin-sorted point ids; 384 independent blocks via per-split LDS cursors.
__global__ __launch_bounds__(1024) void reorder_kernel(
    const unsigned short* __restrict__ bins, const unsigned* __restrict__ offS,
    unsigned* __restrict__ S) {
    __shared__ unsigned cur[NBINS];
    int blk   = blockIdx.x;
    int split = blk & (SPLIT - 1);
    int bp    = blk >> 4;
    int b     = bp / 3, plane = bp - 3 * b;
    const unsigned* osb = offS + (size_t)blk * NBINS;
    for (int i = threadIdx.x; i < NBINS; i += 1024) cur[i] = osb[i];
    __syncthreads();
    const unsigned* src = (const unsigned*)(bins + ((size_t)plane * NB + b) * NPTS
                                                 + (size_t)split * TILE);
    unsigned nbase = (unsigned)(split * TILE);
    unsigned* Sp = S + (size_t)bp * NPTS;
    for (int j = threadIdx.x; j < TILE / 2; j += 1024) {
        unsigned u  = src[j];
        unsigned p0 = atomicAdd(&cur[u & 0xffffu], 1u);
        Sp[p0] = nbase + 2 * j;
        unsigned p1 = atomicAdd(&cur[u >> 16], 1u);
        Sp[p1] = nbase + 2 * j + 1;
    }
}

// feat (b, C, N) fp32 -> ftT (b, n, c) bf16 (RNE). One point = 64 B line.
constexpr int TTILES = (NPTS + 255) / 256;   // 782
__global__ __launch_bounds__(256) void transpose_kernel(
    const float* __restrict__ feat, unsigned short* __restrict__ ftT) {
    int b = blockIdx.x / TTILES;
    int n = (blockIdx.x % TTILES) * 256 + threadIdx.x;
    if (n >= NPTS) return;
    const float* fb = feat + (size_t)b * NC * NPTS + n;
    unsigned pk[16];
#pragma unroll
    for (int c = 0; c < 16; ++c) {
        unsigned u0 = __float_as_uint(fb[(size_t)(2 * c) * NPTS]);
        unsigned u1 = __float_as_uint(fb[(size_t)(2 * c + 1) * NPTS]);
        unsigned r0 = (u0 + 0x7fffu + ((u0 >> 16) & 1u)) >> 16;   // bf16 RNE
        unsigned r1 = (u1 + 0x7fffu + ((u1 >> 16) & 1u)) >> 16;
        pk[c] = r0 | (r1 << 16);
    }
    uint4* dst = (uint4*)(ftT + ((size_t)b * NPTS + n) * NC);
#pragma unroll
    for (int q = 0; q < 4; ++q)
        dst[q] = make_uint4(pk[4 * q], pk[4 * q + 1], pk[4 * q + 2], pk[4 * q + 3]);
}

__device__ __forceinline__ void accum8(float* acc, uint4 v) {
    acc[0] += __uint_as_float(v.x << 16);
    acc[1] += __uint_as_float(v.x & 0xffff0000u);
    acc[2] += __uint_as_float(v.y << 16);
    acc[3] += __uint_as_float(v.y & 0xffff0000u);
    acc[4] += __uint_as_float(v.z << 16);
    acc[5] += __uint_as_float(v.z & 0xffff0000u);
    acc[6] += __uint_as_float(v.w << 16);
    acc[7] += __uint_as_float(v.w & 0xffff0000u);
}

// One LANE per bin (R6 design, proven fast): each lane accumulates all 32
// channels in registers. Per-lane private addresses; 2-pt unroll keeps
// 8 independent dwordx4 loads in flight per lane. Coalesced stores
// (consecutive lanes = consecutive bins).
__global__ __launch_bounds__(256) void gather_kernel(
    const unsigned* __restrict__ off, const unsigned* __restrict__ S,
    const unsigned short* __restrict__ ftT, float* __restrict__ out) {
    int bp  = blockIdx.x >> 6;                    // 64 blocks per bp
    int bin = ((blockIdx.x & 63) << 8) | threadIdx.x;
    int b   = bp / 3;
    const unsigned* op = off + (size_t)bp * NBINS;   // exclusive scan
    unsigned s = op[bin];
    unsigned e = (bin < NBINS - 1) ? op[bin + 1] : (unsigned)NPTS;
    const unsigned* Sp = S + (size_t)bp * NPTS;
    const unsigned short* fb = ftT + (size_t)b * NPTS * NC;
    float acc[NC];
#pragma unroll
    for (int c = 0; c < NC; ++c) acc[c] = 0.0f;
    unsigned p = s;
    for (; p + 2 <= e; p += 2) {
        unsigned n0 = Sp[p], n1 = Sp[p + 1];
        const uint4* q0 = (const uint4*)(fb + (size_t)n0 * NC);
        const uint4* q1 = (const uint4*)(fb + (size_t)n1 * NC);
        uint4 a0 = q0[0], a1 = q0[1], a2 = q0[2], a3 = q0[3];
        uint4 b0 = q1[0], b1 = q1[1], b2 = q1[2], b3 = q1[3];
        accum8(acc +  0, a0); accum8(acc +  8, a1);
        accum8(acc + 16, a2); accum8(acc + 24, a3);
        accum8(acc +  0, b0); accum8(acc +  8, b1);
        accum8(acc + 16, b2); accum8(acc + 24, b3);
    }
    if (p < e) {
        unsigned n0 = Sp[p];
        const uint4* q0 = (const uint4*)(fb + (size_t)n0 * NC);
        uint4 a0 = q0[0], a1 = q0[1], a2 = q0[2], a3 = q0[3];
        accum8(acc +  0, a0); accum8(acc +  8, a1);
        accum8(acc + 16, a2); accum8(acc + 24, a3);
    }
    float inv = 1.0f / fmaxf((float)(e - s), 1.0f);   // empty bins -> 0
    float* ob = out + (size_t)bp * NC * NBINS + bin;
#pragma unroll
    for (int c = 0; c < NC; ++c) ob[(size_t)c * NBINS] = acc[c] * inv;
}

// ---------- fallback (round-3 verified path; needs only bins + cnt) ----------
constexpr int CHUNKS = NPTS / 8;
__global__ __launch_bounds__(1024) void count_fb_kernel(
    const unsigned short* __restrict__ bins, unsigned* __restrict__ cnt) {
    __shared__ unsigned hist[NBINS];
    int blk   = blockIdx.x;
    int split = blk & (SPLIT - 1);
    int bp    = blk >> 4;
    int b     = bp / 3, plane = bp - 3 * b;
    for (int i = threadIdx.x; i < NBINS; i += 1024) hist[i] = 0u;
    __syncthreads();
    const unsigned short* src = bins + ((size_t)plane * NB + b) * NPTS
                                     + (size_t)split * TILE;
    for (int n = threadIdx.x; n < TILE; n += 1024) atomicAdd(&hist[src[n]], 1u);
    __syncthreads();
    unsigned* dst = cnt + (size_t)bp * NBINS;
    for (int i = threadIdx.x; i < NBINS; i += 1024) {
        unsigned v = hist[i];
        if (v) atomicAdd(&dst[i], v);
    }
}
__global__ __launch_bounds__(1024) void scatter_kernel(
    const unsigned short* __restrict__ bins, const float* __restrict__ feat,
    const unsigned* __restrict__ cnt, float* __restrict__ out) {
    __shared__ float hist[NBINS];
    int blk = blockIdx.x, b = blk / 96;
    int rem = blk - b * 96, plane = rem >> 5, ch = rem & 31;
    for (int i = threadIdx.x; i < NBINS; i += 1024) hist[i] = 0.0f;
    __syncthreads();
    const uint4*  bp4 = (const uint4*)(bins + ((size_t)plane * NB + b) * NPTS);
    const float4* fp4 = (const float4*)(feat + ((size_t)b * NC + ch) * NPTS);
    for (int p = threadIdx.x; p < CHUNKS; p += 1024) {
        uint4 bb = bp4[p];
        float4 f0 = fp4[2 * p], f1 = fp4[2 * p + 1];
        atomicAdd(&hist[bb.x & 0xffffu], f0.x);
        atomicAdd(&hist[bb.x >> 16],     f0.y);
        atomicAdd(&hist[bb.y & 0xffffu], f0.z);
        atomicAdd(&hist[bb.y >> 16],     f0.w);
        atomicAdd(&hist[bb.z & 0xffffu], f1.x);
        atomicAdd(&hist[bb.z >> 16],     f1.y);
        atomicAdd(&hist[bb.w & 0xffffu], f1.z);
        atomicAdd(&hist[bb.w >> 16],     f1.w);
    }
    __syncthreads();
    const unsigned* cb = cnt + (size_t)(b * 3 + plane) * NBINS;
    float* ob = out + (((size_t)b * 3 + plane) * NC + ch) * (size_t)NBINS;
    for (int i = threadIdx.x; i < NBINS; i += 1024)
        ob[i] = hist[i] / fmaxf((float)cb[i], 1.0f);
}

extern "C" void kernel_launch(void* const* d_in, const int* in_sizes, int n_in,
                              void* d_out, int out_size, void* d_ws, size_t ws_size,
                              hipStream_t stream) {
    const float* xyz  = (const float*)d_in[0];         // (B, N, 3)
    const float* feat = (const float*)d_in[1];         // (B, C, N)
    float* out = (float*)d_out;                        // (B, 3, C, R, R)
    char* ws = (char*)d_ws;
    unsigned short* bins = (unsigned short*)ws;

    int total_pts = NB * NPTS;
    bin_kernel<<<(total_pts + 255) / 256, 256, 0, stream>>>(xyz, bins);

    if (ws_size >= WS_NEED) {
        unsigned short* cntS = (unsigned short*)(ws + OFF_CNTS);
        unsigned* offS = (unsigned*)(ws + OFF_OFFS);
        unsigned* off  = (unsigned*)(ws + OFF_OFF);
        unsigned* S    = (unsigned*)(ws + OFF_S);
        unsigned short* ftT = (unsigned short*)ws;     // overlays phase-1 bufs
        count_kernel<<<NB * 3 * SPLIT, 1024, 0, stream>>>(bins, cntS);
        scan_kernel<<<NB * 3, 1024, 0, stream>>>(cntS, off, offS);
        reorder_kernel<<<NB * 3 * SPLIT, 1024, 0, stream>>>(bins, offS, S);
        transpose_kernel<<<NB * TTILES, 256, 0, stream>>>(feat, ftT);  // after reorder!
        gather_kernel<<<NB * 3 * 64, 256, 0, stream>>>(off, S, ftT, out);
    } else {
        unsigned* cnt = (unsigned*)(ws + OFF_CNTS);
        hipMemsetAsync(cnt, 0, (size_t)NB * 3 * NBINS * sizeof(unsigned), stream);
        count_fb_kernel<<<NB * 3 * SPLIT, 1024, 0, stream>>>(bins, cnt);
        scatter_kernel<<<NB * 3 * NC, 1024, 0, stream>>>(bins, feat, cnt, out);
    }
}

// Round 5
// 455.641 us; speedup vs baseline: 2.6507x; 1.1580x over previous
//
#include <hip/hip_runtime.h>

// TriPlanePC2Encoder: scatter-mean of point features onto 3 canonical planes.
// B=8, N=200000, C=32, R=128. out[b, plane, c, row, col], plane order xy,yz,xz.
//
// Round 10: two-level sort. R9 (527us) back-solve: reorder ~140us dominated
// by 16x write amp on 4B random scatter (R6 measured 309MB WRITE for 19.2MB).
//   bin -> count (512 sbin hist; R8-verified) -> sscan (R8-verified) ->
//   reorder1 (512 sbin LDS cursors, ~24-entry runs => ~2x amp; R8-verified)
//   -> localsort (NEW: one wave per sbin; count[32]+shfl-scan+scatter ->
//   per-bin off[] + point-sorted S2, coalesced) -> transpose -> gather
//   (R9-verified bin-per-lane register accumulation, unchanged).
// Harness note: ~120us fillBufferAligned (ws poison, 819MB) sits inside the
// timed window each iteration; our kernel budget is dur_us - 120.
// R6 lesson: global atomic-with-return per point = latency death.
// R7/R8 lesson: group-uniform index loads + LDS fp32 atomic accumulation is
//   ~15x below latency model; per-lane addrs + register accum is the pattern.

constexpr int R     = 128;
constexpr int NBINS = R * R;        // 16384
constexpr int NPTS  = 200000;
constexpr int NB    = 8;
constexpr int NC    = 32;
constexpr int SPLIT = 16;           // sort tiles per (b,plane)
constexpr int TILE  = NPTS / SPLIT; // 12500 (fits u16 counts)
constexpr int NSB   = 512;          // super-bins (32 bins each)

// ws layout:
//  phase1 (dead after localsort, overlaid by ftT later):
//    bins  u16 [3][NB][NPTS]       @ 0           (9,600,000)
//    scntS u16 [24][16][512]       @ 9,600,000   (393,216)
//    soffS u32 [24][16][512]       @ 9,993,216   (786,432)
//    S1    u32 [24][NPTS]          @ 10,779,648  (19,200,000) end 29,979,648
//  phase2: ftT bf16 [NB][NPTS][NC] @ 0           (102,400,000)
//  persistent tail:
//    off  u32 [24][NBINS]          @ 102,400,000 (1,572,864)
//    S2   u32 [24][NPTS]           @ 103,972,864 (19,200,000)
//    soffB u32 [24][513]           @ 123,172,864 (49,248)     end 123,222,112
constexpr size_t OFF_SCNT  = 9600000;
constexpr size_t OFF_SOFFS = 9993216;
constexpr size_t OFF_S1    = 10779648;
constexpr size_t OFF_OFF   = 102400000;
constexpr size_t OFF_S2    = 103972864;
constexpr size_t OFF_SOFFB = 123172864;
constexpr size_t WS_NEED   = 123222112;
constexpr size_t OFF_CNTFB = 9600000;   // fallback-only cnt region

__device__ __forceinline__ int coord_bin(float p) {
    // xyz_norm = (p+1)/2 - 0.5 ; then /(1+eps) + 0.5 ; clip ; *R ; trunc
    float v = (p + 1.0f) * 0.5f - 0.5f;
    float t = v / 1.00001f + 0.5f;                     // IEEE fp32 divide
    t = fminf(fmaxf(t, 0.0f), (float)(1.0 - 1e-5));
    return (int)(t * 128.0f);
}

__global__ __launch_bounds__(256) void bin_kernel(
    const float* __restrict__ xyz, unsigned short* __restrict__ bins) {
    int i = blockIdx.x * 256 + threadIdx.x;            // over B*N
    if (i >= NB * NPTS) return;
    float x = xyz[3 * (size_t)i + 0];
    float y = xyz[3 * (size_t)i + 1];
    float z = xyz[3 * (size_t)i + 2];
    int ix = coord_bin(x), iy = coord_bin(y), iz = coord_bin(z);
    // plane dims: xy=(0,1) yz=(1,2) xz=(0,2); lin = idx_d0 + R*idx_d1
    bins[0 * (size_t)NB * NPTS + i] = (unsigned short)(ix + R * iy);
    bins[1 * (size_t)NB * NPTS + i] = (unsigned short)(iy + R * iz);
    bins[2 * (size_t)NB * NPTS + i] = (unsigned short)(ix + R * iz);
}

// Per-(bp,split) 512-entry super-bin histogram -> scntS u16. (R8-verified)
__global__ __launch_bounds__(1024) void count_kernel(
    const unsigned short* __restrict__ bins, unsigned short* __restrict__ scntS) {
    __shared__ unsigned h[NSB];
    int blk   = blockIdx.x;
    int split = blk & (SPLIT - 1);
    int bp    = blk >> 4;
    int b     = bp / 3, plane = bp - 3 * b;
    if (threadIdx.x < NSB) h[threadIdx.x] = 0u;
    __syncthreads();
    const unsigned* src = (const unsigned*)(bins + ((size_t)plane * NB + b) * NPTS
                                                 + (size_t)split * TILE);
    for (int j = threadIdx.x; j < TILE / 2; j += 1024) {
        unsigned u = src[j];
        atomicAdd(&h[(u & 0xffffu) >> 5], 1u);
        atomicAdd(&h[(u >> 16) >> 5], 1u);
    }
    __syncthreads();
    unsigned short* dst = scntS + (size_t)blk * NSB;
    if (threadIdx.x < NSB) dst[threadIdx.x] = (unsigned short)h[threadIdx.x];
}

// Per-bp: per-split running offsets + block-wide excl scan of 512 sbins.
// (R8-verified)
__global__ __launch_bounds__(512) void sscan_kernel(
    const unsigned short* __restrict__ scntS, unsigned* __restrict__ soffS,
    unsigned* __restrict__ soffB) {
    __shared__ unsigned ts[NSB];
    int bp = blockIdx.x, t = threadIdx.x;
    const unsigned short* cb = scntS + (size_t)bp * SPLIT * NSB;
    unsigned rel[SPLIT];
    unsigned run = 0;
#pragma unroll
    for (int s = 0; s < SPLIT; ++s) {
        rel[s] = run;
        run += cb[(size_t)s * NSB + t];
    }
    ts[t] = run;
    __syncthreads();
    for (int o = 1; o < NSB; o <<= 1) {                // Hillis-Steele incl.
        unsigned a = (t >= o) ? ts[t - o] : 0u;
        __syncthreads();
        ts[t] += a;
        __syncthreads();
    }
    unsigned base = ts[t] - run;                       // exclusive
    unsigned* osb = soffS + (size_t)bp * SPLIT * NSB;
#pragma unroll
    for (int s = 0; s < SPLIT; ++s) osb[(size_t)s * NSB + t] = base + rel[s];
    soffB[bp * 513 + t] = base;
    if (t == NSB - 1) soffB[bp * 513 + NSB] = ts[t];   // sentinel = NPTS
}

// Super-bin sort via per-split LDS cursors. Runs per (split,sbin) ~24
// entries -> write-combined, ~2x amp instead of 16x. (R8-verified)
// entry = (point_id << 5) | (bin & 31)
__global__ __launch_bounds__(1024) void reorder_kernel(
    const unsigned short* __restrict__ bins, const unsigned* __restrict__ soffS,
    unsigned* __restrict__ S1) {
    __shared__ unsigned cur[NSB];
    int blk   = blockIdx.x;
    int split = blk & (SPLIT - 1);
    int bp    = blk >> 4;
    int b     = bp / 3, plane = bp - 3 * b;
    const unsigned* osb = soffS + (size_t)blk * NSB;
    if (threadIdx.x < NSB) cur[threadIdx.x] = osb[threadIdx.x];
    __syncthreads();
    const unsigned* src = (const unsigned*)(bins + ((size_t)plane * NB + b) * NPTS
                                                 + (size_t)split * TILE);
    unsigned nbase = (unsigned)(split * TILE);
    unsigned* ep = S1 + (size_t)bp * NPTS;
    for (int j = threadIdx.x; j < TILE / 2; j += 1024) {
        unsigned u  = src[j];
        unsigned l0 = u & 0xffffu, l1 = u >> 16;
        unsigned p0 = atomicAdd(&cur[l0 >> 5], 1u);
        ep[p0] = ((nbase + 2u * j) << 5) | (l0 & 31u);
        unsigned p1 = atomicAdd(&cur[l1 >> 5], 1u);
        ep[p1] = ((nbase + 2u * j + 1u) << 5) | (l1 & 31u);
    }
}

// NEW: one wave per super-bin. Sorts the sbin's ~390 entries into per-bin
// order: pass1 counts 32 bins (LDS), shfl exclusive scan, write per-bin
// global offsets; pass2 scatters point ids to S2 (contiguous sbin region,
// cache-resident). No capacity limit; empty sbins no-op.
__global__ __launch_bounds__(64) void localsort_kernel(
    const unsigned* __restrict__ soffB, const unsigned* __restrict__ S1,
    unsigned* __restrict__ off, unsigned* __restrict__ S2) {
    __shared__ unsigned cnt[32], cur[32];
    int bp = blockIdx.x >> 9;                          // 512 blocks per bp
    int sb = blockIdx.x & 511;
    int t  = threadIdx.x;
    unsigned s = soffB[bp * 513 + sb], e = soffB[bp * 513 + sb + 1];
    if (t < 32) cnt[t] = 0u;
    __syncthreads();
    const unsigned* S1p = S1 + (size_t)bp * NPTS;
    for (unsigned j = s + t; j < e; j += 64)
        atomicAdd(&cnt[S1p[j] & 31u], 1u);
    __syncthreads();
    unsigned v = (t < 32) ? cnt[t] : 0u;
#pragma unroll
    for (int o = 1; o < 32; o <<= 1) {                 // inclusive shfl scan
        unsigned u = __shfl_up(v, o, 32);
        if ((t & 31) >= o) v += u;
    }
    if (t < 32) {
        unsigned excl = v - cnt[t];
        cur[t] = excl;
        off[(size_t)bp * NBINS + sb * 32 + t] = s + excl;
    }
    __syncthreads();
    unsigned* S2p = S2 + (size_t)bp * NPTS;
    for (unsigned j = s + t; j < e; j += 64) {
        unsigned en = S1p[j];
        unsigned p  = atomicAdd(&cur[en & 31u], 1u);
        S2p[s + p] = en >> 5;
    }
}

// feat (b, C, N) fp32 -> ftT (b, n, c) bf16 (RNE). One point = 64 B line.
constexpr int TTILES = (NPTS + 255) / 256;   // 782
__global__ __launch_bounds__(256) void transpose_kernel(
    const float* __restrict__ feat, unsigned short* __restrict__ ftT) {
    int b = blockIdx.x / TTILES;
    int n = (blockIdx.x % TTILES) * 256 + threadIdx.x;
    if (n >= NPTS) return;
    const float* fb = feat + (size_t)b * NC * NPTS + n;
    unsigned pk[16];
#pragma unroll
    for (int c = 0; c < 16; ++c) {
        unsigned u0 = __float_as_uint(fb[(size_t)(2 * c) * NPTS]);
        unsigned u1 = __float_as_uint(fb[(size_t)(2 * c + 1) * NPTS]);
        unsigned r0 = (u0 + 0x7fffu + ((u0 >> 16) & 1u)) >> 16;   // bf16 RNE
        unsigned r1 = (u1 + 0x7fffu + ((u1 >> 16) & 1u)) >> 16;
        pk[c] = r0 | (r1 << 16);
    }
    uint4* dst = (uint4*)(ftT + ((size_t)b * NPTS + n) * NC);
#pragma unroll
    for (int q = 0; q < 4; ++q)
        dst[q] = make_uint4(pk[4 * q], pk[4 * q + 1], pk[4 * q + 2], pk[4 * q + 3]);
}

__device__ __forceinline__ void accum8(float* acc, uint4 v) {
    acc[0] += __uint_as_float(v.x << 16);
    acc[1] += __uint_as_float(v.x & 0xffff0000u);
    acc[2] += __uint_as_float(v.y << 16);
    acc[3] += __uint_as_float(v.y & 0xffff0000u);
    acc[4] += __uint_as_float(v.z << 16);
    acc[5] += __uint_as_float(v.z & 0xffff0000u);
    acc[6] += __uint_as_float(v.w << 16);
    acc[7] += __uint_as_float(v.w & 0xffff0000u);
}

// One LANE per bin (R9-verified): each lane accumulates all 32 channels in
// registers. Per-lane private addresses; 2-pt unroll keeps 8 independent
// dwordx4 loads in flight per lane. Coalesced stores.
__global__ __launch_bounds__(256) void gather_kernel(
    const unsigned* __restrict__ off, const unsigned* __restrict__ S2,
    const unsigned short* __restrict__ ftT, float* __restrict__ out) {
    int bp  = blockIdx.x >> 6;                    // 64 blocks per bp
    int bin = ((blockIdx.x & 63) << 8) | threadIdx.x;
    int b   = bp / 3;
    const unsigned* op = off + (size_t)bp * NBINS;   // exclusive scan
    unsigned s = op[bin];
    unsigned e = (bin < NBINS - 1) ? op[bin + 1] : (unsigned)NPTS;
    const unsigned* Sp = S2 + (size_t)bp * NPTS;
    const unsigned short* fb = ftT + (size_t)b * NPTS * NC;
    float acc[NC];
#pragma unroll
    for (int c = 0; c < NC; ++c) acc[c] = 0.0f;
    unsigned p = s;
    for (; p + 2 <= e; p += 2) {
        unsigned n0 = Sp[p], n1 = Sp[p + 1];
        const uint4* q0 = (const uint4*)(fb + (size_t)n0 * NC);
        const uint4* q1 = (const uint4*)(fb + (size_t)n1 * NC);
        uint4 a0 = q0[0], a1 = q0[1], a2 = q0[2], a3 = q0[3];
        uint4 b0 = q1[0], b1 = q1[1], b2 = q1[2], b3 = q1[3];
        accum8(acc +  0, a0); accum8(acc +  8, a1);
        accum8(acc + 16, a2); accum8(acc + 24, a3);
        accum8(acc +  0, b0); accum8(acc +  8, b1);
        accum8(acc + 16, b2); accum8(acc + 24, b3);
    }
    if (p < e) {
        unsigned n0 = Sp[p];
        const uint4* q0 = (const uint4*)(fb + (size_t)n0 * NC);
        uint4 a0 = q0[0], a1 = q0[1], a2 = q0[2], a3 = q0[3];
        accum8(acc +  0, a0); accum8(acc +  8, a1);
        accum8(acc + 16, a2); accum8(acc + 24, a3);
    }
    float inv = 1.0f / fmaxf((float)(e - s), 1.0f);   // empty bins -> 0
    float* ob = out + (size_t)bp * NC * NBINS + bin;
#pragma unroll
    for (int c = 0; c < NC; ++c) ob[(size_t)c * NBINS] = acc[c] * inv;
}

// ---------- fallback (round-3 verified path; needs only bins + cnt) ----------
constexpr int CHUNKS = NPTS / 8;
__global__ __launch_bounds__(1024) void count_fb_kernel(
    const unsigned short* __restrict__ bins, unsigned* __restrict__ cnt) {
    __shared__ unsigned hist[NBINS];
    int blk   = blockIdx.x;
    int split = blk & (SPLIT - 1);
    int bp    = blk >> 4;
    int b     = bp / 3, plane = bp - 3 * b;
    for (int i = threadIdx.x; i < NBINS; i += 1024) hist[i] = 0u;
    __syncthreads();
    const unsigned short* src = bins + ((size_t)plane * NB + b) * NPTS
                                     + (size_t)split * TILE;
    for (int n = threadIdx.x; n < TILE; n += 1024) atomicAdd(&hist[src[n]], 1u);
    __syncthreads();
    unsigned* dst = cnt + (size_t)bp * NBINS;
    for (int i = threadIdx.x; i < NBINS; i += 1024) {
        unsigned v = hist[i];
        if (v) atomicAdd(&dst[i], v);
    }
}
__global__ __launch_bounds__(1024) void scatter_kernel(
    const unsigned short* __restrict__ bins, const float* __restrict__ feat,
    const unsigned* __restrict__ cnt, float* __restrict__ out) {
    __shared__ float hist[NBINS];
    int blk = blockIdx.x, b = blk / 96;
    int rem = blk - b * 96, plane = rem >> 5, ch = rem & 31;
    for (int i = threadIdx.x; i < NBINS; i += 1024) hist[i] = 0.0f;
    __syncthreads();
    const uint4*  bp4 = (const uint4*)(bins + ((size_t)plane * NB + b) * NPTS);
    const float4* fp4 = (const float4*)(feat + ((size_t)b * NC + ch) * NPTS);
    for (int p = threadIdx.x; p < CHUNKS; p += 1024) {
        uint4 bb = bp4[p];
        float4 f0 = fp4[2 * p], f1 = fp4[2 * p + 1];
        atomicAdd(&hist[bb.x & 0xffffu], f0.x);
        atomicAdd(&hist[bb.x >> 16],     f0.y);
        atomicAdd(&hist[bb.y & 0xffffu], f0.z);
        atomicAdd(&hist[bb.y >> 16],     f0.w);
        atomicAdd(&hist[bb.z & 0xffffu], f1.x);
        atomicAdd(&hist[bb.z >> 16],     f1.y);
        atomicAdd(&hist[bb.w & 0xffffu], f1.z);
        atomicAdd(&hist[bb.w >> 16],     f1.w);
    }
    __syncthreads();
    const unsigned* cb = cnt + (size_t)(b * 3 + plane) * NBINS;
    float* ob = out + (((size_t)b * 3 + plane) * NC + ch) * (size_t)NBINS;
    for (int i = threadIdx.x; i < NBINS; i += 1024)
        ob[i] = hist[i] / fmaxf((float)cb[i], 1.0f);
}

extern "C" void kernel_launch(void* const* d_in, const int* in_sizes, int n_in,
                              void* d_out, int out_size, void* d_ws, size_t ws_size,
                              hipStream_t stream) {
    const float* xyz  = (const float*)d_in[0];         // (B, N, 3)
    const float* feat = (const float*)d_in[1];         // (B, C, N)
    float* out = (float*)d_out;                        // (B, 3, C, R, R)
    char* ws = (char*)d_ws;
    unsigned short* bins = (unsigned short*)ws;

    int total_pts = NB * NPTS;
    bin_kernel<<<(total_pts + 255) / 256, 256, 0, stream>>>(xyz, bins);

    if (ws_size >= WS_NEED) {
        unsigned short* scntS = (unsigned short*)(ws + OFF_SCNT);
        unsigned* soffS = (unsigned*)(ws + OFF_SOFFS);
        unsigned* S1    = (unsigned*)(ws + OFF_S1);
        unsigned* off   = (unsigned*)(ws + OFF_OFF);
        unsigned* S2    = (unsigned*)(ws + OFF_S2);
        unsigned* soffB = (unsigned*)(ws + OFF_SOFFB);
        unsigned short* ftT = (unsigned short*)ws;     // overlays phase-1 bufs
        count_kernel<<<NB * 3 * SPLIT, 1024, 0, stream>>>(bins, scntS);
        sscan_kernel<<<NB * 3, 512, 0, stream>>>(scntS, soffS, soffB);
        reorder_kernel<<<NB * 3 * SPLIT, 1024, 0, stream>>>(bins, soffS, S1);
        localsort_kernel<<<NB * 3 * NSB, 64, 0, stream>>>(soffB, S1, off, S2);
        transpose_kernel<<<NB * TTILES, 256, 0, stream>>>(feat, ftT);  // after localsort!
        gather_kernel<<<NB * 3 * 64, 256, 0, stream>>>(off, S2, ftT, out);
    } else {
        unsigned* cnt = (unsigned*)(ws + OFF_CNTFB);
        hipMemsetAsync(cnt, 0, (size_t)NB * 3 * NBINS * sizeof(unsigned), stream);
        count_fb_kernel<<<NB * 3 * SPLIT, 1024, 0, stream>>>(bins, cnt);
        scatter_kernel<<<NB * 3 * NC, 1024, 0, stream>>>(bins, feat, cnt, out);
    }
}